// Round 8
// baseline (539.441 us; speedup 1.0000x reference)
//
#include <hip/hip_runtime.h>
#include <hip/hip_bf16.h>
#include <math.h>

// ---------------------------------------------------------------------------
// GAT 2-layer forward. CSR aggregation (channel-sliced, XCD-affine), bf16
// gather table, attention weights recomputed inline.
//
// Once per call: counting-sort edges by dst -> rowptr[N+1], esrc[]
// Per layer:
//   1) gemm_fused: h = x@W^T -> hq[n][c] packed bf16x2 + fused si/sj scores
//      (+ zeroes Z for the following z_sum)
//   2) z_sum (node-parallel): Z[hd] = sum_e exp(leaky(si[n]+sj[src]))
//      (global softmax denom; max-shift skipped — logits bounded,
//      mathematically identical)
//   3) csr_agg_sliced: blocks with blockIdx%8==s handle channels [8s,8s+8)
//      only -> per-slice hq working set = N*32B = 1.6 MB, L2-resident on one
//      XCD (affinity heuristic only; correctness independent of mapping).
//      Wave = 8 edges x 8 channels; xor-shuffle reduce; fused epilogue.
// ---------------------------------------------------------------------------

__device__ __forceinline__ unsigned f2bf(float x) {  // fp32 -> bf16 (RNE)
  unsigned u = __float_as_uint(x);
  return (u + 0x7fffu + ((u >> 16) & 1u)) >> 16;
}
__device__ __forceinline__ float bflo(unsigned p) { return __uint_as_float(p << 16); }
__device__ __forceinline__ float bfhi(unsigned p) { return __uint_as_float(p & 0xffff0000u); }

// Register-tiled GEMM + fused scores. Block: 256 = 32 thread-cols x 8 rows.
template <int FIN>
__global__ __launch_bounds__(256) void gemm_fused(
    const float* __restrict__ x, const float* __restrict__ W,
    const float* __restrict__ att, unsigned* __restrict__ hq,
    float* __restrict__ si, float* __restrict__ sj,
    float* __restrict__ Z, int N) {
  __shared__ __align__(16) float xs[32][68];
  __shared__ __align__(16) float ws[32][132];

  const int tid = threadIdx.x;
  const int tc = tid & 31;
  const int tr = tid >> 5;
  const int lane = tid & 63;
  const int n0 = blockIdx.x * 64;

  if (blockIdx.x == 0 && tid < 2) Z[tid] = 0.f;  // consumer is a later dispatch

  const float4* x4 = (const float4*)x;
  const float4* W4 = (const float4*)W;

  float acc[8][4];
#pragma unroll
  for (int i = 0; i < 8; ++i)
#pragma unroll
    for (int j = 0; j < 4; ++j) acc[i][j] = 0.f;

  for (int kc = 0; kc < FIN; kc += 32) {
    const int kc4 = kc >> 2;
    __syncthreads();
#pragma unroll
    for (int r = 0; r < 2; ++r) {
      int i = tid + r * 256;
      int node = i >> 3, kq = i & 7;
      int gn = n0 + node;
      float4 v = make_float4(0.f, 0.f, 0.f, 0.f);
      if (gn < N) v = x4[(size_t)gn * (FIN / 4) + kc4 + kq];
      xs[kq * 4 + 0][node] = v.x;
      xs[kq * 4 + 1][node] = v.y;
      xs[kq * 4 + 2][node] = v.z;
      xs[kq * 4 + 3][node] = v.w;
    }
#pragma unroll
    for (int r = 0; r < 4; ++r) {
      int i = tid + r * 256;
      int col = i >> 3, kq = i & 7;
      float4 v = W4[(size_t)col * (FIN / 4) + kc4 + kq];
      ws[kq * 4 + 0][col] = v.x;
      ws[kq * 4 + 1][col] = v.y;
      ws[kq * 4 + 2][col] = v.z;
      ws[kq * 4 + 3][col] = v.w;
    }
    __syncthreads();
#pragma unroll
    for (int k = 0; k < 32; ++k) {
      float4 wv = *(const float4*)&ws[k][tc * 4];
      float4 a0 = *(const float4*)&xs[k][tr * 8];
      float4 a1 = *(const float4*)&xs[k][tr * 8 + 4];
      float av[8] = {a0.x, a0.y, a0.z, a0.w, a1.x, a1.y, a1.z, a1.w};
      float wvv[4] = {wv.x, wv.y, wv.z, wv.w};
#pragma unroll
      for (int i = 0; i < 8; ++i)
#pragma unroll
        for (int j = 0; j < 4; ++j) acc[i][j] += av[i] * wvv[j];
    }
  }

  // ------- epilogue: pack bf16x2 h + fused attention scores -------
  const int hd = tc >> 4;
  const int ch = (tc & 15) * 4;
  float ai[4], aj[4];
#pragma unroll
  for (int j = 0; j < 4; ++j) {
    ai[j] = att[hd * 128 + ch + j];
    aj[j] = att[hd * 128 + 64 + ch + j];
  }
#pragma unroll
  for (int i = 0; i < 8; ++i) {
    int node = n0 + tr * 8 + i;
    float sip = 0.f, sjp = 0.f;
    unsigned w[4];
#pragma unroll
    for (int j = 0; j < 4; ++j) {
      float v = acc[i][j];
      sip += v * ai[j];
      sjp += v * aj[j];
      float other = __shfl_xor(v, 16, 64);  // partner head, same channel
      float h0 = (tc < 16) ? v : other;
      float h1 = (tc < 16) ? other : v;
      w[j] = f2bf(h0) | (f2bf(h1) << 16);
    }
#pragma unroll
    for (int off = 8; off; off >>= 1) {
      sip += __shfl_down(sip, off, 64);
      sjp += __shfl_down(sjp, off, 64);
    }
    bool valid = node < N;
    if (valid && tc < 16) {
      *(uint4*)&hq[(size_t)node * 64 + ch] = make_uint4(w[0], w[1], w[2], w[3]);
    }
    if (valid && (lane & 15) == 0) {
      int hh = (lane >> 4) & 1;
      si[node * 2 + hh] = sip;
      sj[node * 2 + hh] = sjp;
    }
  }
}

// node-parallel Z reduction: thread n walks its CSR range, no stores
__global__ __launch_bounds__(256) void z_sum(
    const int* __restrict__ rowptr, const int* __restrict__ esrc,
    const float2* __restrict__ si2, const float2* __restrict__ sj2,
    float* __restrict__ Z, int N) {
  float z0 = 0.f, z1 = 0.f;
  int tid = blockIdx.x * blockDim.x + threadIdx.x;
  int stride = gridDim.x * blockDim.x;
  for (int n = tid; n < N; n += stride) {
    int beg = rowptr[n], end = rowptr[n + 1];
    float2 siv = si2[n];
    for (int k = beg; k < end; ++k) {
      int s = esrc[k];
      float2 sjv = sj2[s];
      float a0 = siv.x + sjv.x;
      float a1 = siv.y + sjv.y;
      a0 = a0 >= 0.f ? a0 : 0.2f * a0;
      a1 = a1 >= 0.f ? a1 : 0.2f * a1;
      z0 += __expf(a0); z1 += __expf(a1);
    }
  }
  __shared__ float r0[4], r1[4];
  int lane = threadIdx.x & 63, w = threadIdx.x >> 6;
#pragma unroll
  for (int off = 32; off; off >>= 1) {
    z0 += __shfl_down(z0, off, 64);
    z1 += __shfl_down(z1, off, 64);
  }
  if (lane == 0) { r0[w] = z0; r1[w] = z1; }
  __syncthreads();
  if (threadIdx.x == 0) {
    atomicAdd(&Z[0], r0[0] + r0[1] + r0[2] + r0[3]);
    atomicAdd(&Z[1], r1[0] + r1[1] + r1[2] + r1[3]);
  }
}

// -------------------- counting sort by dst --------------------
__global__ __launch_bounds__(256) void hist_dst(
    const int* __restrict__ dstE, int* __restrict__ deg, int E, int Etot) {
  int tid = blockIdx.x * blockDim.x + threadIdx.x;
  int stride = gridDim.x * blockDim.x;
  for (int e = tid; e < Etot; e += stride) {
    int d = (e < E) ? dstE[e] : e - E;
    atomicAdd(&deg[d], 1);
  }
}

__global__ __launch_bounds__(256) void scan_blocks(
    const int* __restrict__ deg, int* __restrict__ rowptr,
    int* __restrict__ bsum, int N) {
  __shared__ int ts[256];
  int b = blockIdx.x, t = threadIdx.x;
  int base = b * 1024 + t * 4;
  int v[4];
#pragma unroll
  for (int j = 0; j < 4; ++j) v[j] = (base + j < N) ? deg[base + j] : 0;
  int tot = v[0] + v[1] + v[2] + v[3];
  ts[t] = tot;
  __syncthreads();
#pragma unroll
  for (int off = 1; off < 256; off <<= 1) {
    int x = (t >= off) ? ts[t - off] : 0;
    __syncthreads();
    ts[t] += x;
    __syncthreads();
  }
  int run = ts[t] - tot;
#pragma unroll
  for (int j = 0; j < 4; ++j) {
    if (base + j < N) rowptr[base + j] = run;
    run += v[j];
  }
  if (t == 255) bsum[b] = ts[255];
}

// folds the bsum scan in: each block serially prefixes bsum (nb<=256) in LDS
__global__ __launch_bounds__(256) void scan_finish(
    int* __restrict__ rowptr, const int* __restrict__ bsum,
    int* __restrict__ cursor, int N, int Etot, int nb) {
  __shared__ int pre[256];
  if (threadIdx.x == 0) {
    int run = 0;
    for (int i = 0; i < nb; ++i) { pre[i] = run; run += bsum[i]; }
  }
  __syncthreads();
  int tid = blockIdx.x * blockDim.x + threadIdx.x;
  int stride = gridDim.x * blockDim.x;
  for (int i = tid; i < N; i += stride) {
    int v = rowptr[i] + pre[i >> 10];
    rowptr[i] = v;
    cursor[i] = v;
  }
  if (tid == 0) rowptr[N] = Etot;
}

// dst-partitioned scatter (8 ranges, XCD-affine via blockIdx%8)
__global__ __launch_bounds__(256) void scatter_part(
    const int* __restrict__ srcE, const int* __restrict__ dstE,
    int* __restrict__ cursor, int* __restrict__ esrc,
    int E, int Etot, int step) {
  const int p = blockIdx.x & 7;
  const int sub = blockIdx.x >> 3;
  const int nsub = gridDim.x >> 3;
  const int lo = p * step;
  const int hi = lo + step;
  int stride = nsub * 256;
  for (int e = sub * 256 + threadIdx.x; e < Etot; e += stride) {
    int d = (e < E) ? dstE[e] : e - E;
    if (d >= lo && d < hi) {
      int s = (e < E) ? srcE[e] : d;
      int pos = atomicAdd(&cursor[d], 1);
      esrc[pos] = s;
    }
  }
}

// channel-sliced aggregation: slice = blockIdx%8 owns channels [8s, 8s+8).
// Wave = 8 edge-groups x 8 channels; per-slice hq footprint 1.6 MB (L2-res).
__global__ __launch_bounds__(256) void csr_agg_sliced(
    const int* __restrict__ rowptr, const int* __restrict__ esrc,
    const unsigned* __restrict__ hq, const float2* __restrict__ si2,
    const float2* __restrict__ sj2, const float* __restrict__ Z,
    const float* __restrict__ bias, float* __restrict__ out,
    int N, int do_relu) {
  const int slice = blockIdx.x & 7;
  const int sub = blockIdx.x >> 3;
  const int nsub = gridDim.x >> 3;
  const int lane = threadIdx.x & 63;
  const int wv = threadIdx.x >> 6;
  const int edge_sub = lane >> 3;   // 0..7
  const int ch = slice * 8 + (lane & 7);
  const int gw = sub * 4 + wv;      // wave id within slice
  const int nw = nsub * 4;

  float z0 = 1.f / (Z[0] + 1e-10f);
  float z1 = 1.f / (Z[1] + 1e-10f);
  float bv = bias[ch];

  for (int n0 = gw; n0 < N; n0 += nw) {
    int n = __builtin_amdgcn_readfirstlane(n0);
    int beg = rowptr[n], end = rowptr[n + 1];
    float2 siv = si2[n];
    float acc0 = 0.f, acc1 = 0.f;
    for (int k0 = beg; k0 < end; k0 += 8) {
      int k = k0 + edge_sub;
      bool valid = k < end;
      int s = esrc[valid ? k : beg];  // beg always valid (self-loops)
      float2 jv = sj2[s];
      float a0 = siv.x + jv.x;
      float a1 = siv.y + jv.y;
      a0 = a0 >= 0.f ? a0 : 0.2f * a0;
      a1 = a1 >= 0.f ? a1 : 0.2f * a1;
      float w0 = valid ? __expf(a0) : 0.f;
      float w1 = valid ? __expf(a1) : 0.f;
      unsigned p = hq[(size_t)s * 64 + ch];
      acc0 += bflo(p) * w0;
      acc1 += bfhi(p) * w1;
    }
    // sum across the 8 edge-groups (lane bits 3..5)
#pragma unroll
    for (int off = 8; off < 64; off <<= 1) {
      acc0 += __shfl_xor(acc0, off, 64);
      acc1 += __shfl_xor(acc1, off, 64);
    }
    if (edge_sub == 0) {
      float r = 0.5f * (acc0 * z0 + acc1 * z1) + bv;
      if (do_relu) r = fmaxf(r, 0.f);
      out[(size_t)n * 64 + ch] = r;
    }
  }
}

extern "C" void kernel_launch(void* const* d_in, const int* in_sizes, int n_in,
                              void* d_out, int out_size, void* d_ws, size_t ws_size,
                              hipStream_t stream) {
  const float* x    = (const float*)d_in[0];
  const int*   ei   = (const int*)d_in[1];   // [2, E] int32
  const float* W1   = (const float*)d_in[2];
  const float* att1 = (const float*)d_in[3];
  const float* b1   = (const float*)d_in[4];
  const float* W2   = (const float*)d_in[5];
  const float* att2 = (const float*)d_in[6];
  const float* b2   = (const float*)d_in[7];
  float* out = (float*)d_out;

  const int N = in_sizes[0] / 128;   // 50000
  const int E = in_sizes[1] / 2;     // 800000
  const int Etot = E + N;
  const int* srcE = ei;
  const int* dstE = ei + E;

  // workspace layout (all segments 16B-aligned)
  unsigned* hq = (unsigned*)d_ws;                 // N*64 packed bf16x2
  float* si    = (float*)(hq + (size_t)N * 64);   // N*2
  float* sj    = si + (size_t)N * 2;              // N*2
  float* Z     = sj + (size_t)N * 2;              // 4
  float* x2    = Z + 4;                           // N*64
  int* rowptr  = (int*)(x2 + (size_t)N * 64);     // N+1
  int* cursor  = rowptr + (N + 1);                // N (deg histogram too)
  int* esrc    = cursor + N;                      // Etot
  int* bsum    = esrc + Etot;                     // up to 256

  dim3 blk(256);
  int nb = (N + 1023) / 1024;
  int ntiles = (N + 63) / 64;
  int step = (N + 7) / 8;

  // ---------- CSR build (shared by both layers) ----------
  hipMemsetAsync(cursor, 0, (size_t)N * sizeof(int), stream);
  hist_dst<<<2048, blk, 0, stream>>>(dstE, cursor, E, Etot);
  scan_blocks<<<nb, blk, 0, stream>>>(cursor, rowptr, bsum, N);
  scan_finish<<<256, blk, 0, stream>>>(rowptr, bsum, cursor, N, Etot, nb);
  scatter_part<<<2048, blk, 0, stream>>>(srcE, dstE, cursor, esrc, E, Etot, step);

  // ---------------- layer 1 ----------------
  gemm_fused<128><<<ntiles, blk, 0, stream>>>(x, W1, att1, hq, si, sj, Z, N);
  z_sum<<<256, blk, 0, stream>>>(rowptr, esrc, (const float2*)si,
                                 (const float2*)sj, Z, N);
  csr_agg_sliced<<<4096, blk, 0, stream>>>(rowptr, esrc, hq, (const float2*)si,
                                           (const float2*)sj, Z, b1, x2, N, 1);

  // ---------------- layer 2 ----------------
  gemm_fused<64><<<ntiles, blk, 0, stream>>>(x2, W2, att2, hq, si, sj, Z, N);
  z_sum<<<256, blk, 0, stream>>>(rowptr, esrc, (const float2*)si,
                                 (const float2*)sj, Z, N);
  csr_agg_sliced<<<4096, blk, 0, stream>>>(rowptr, esrc, hq, (const float2*)si,
                                           (const float2*)sj, Z, b2, out, N, 0);
}

// Round 9
// 318.194 us; speedup vs baseline: 1.6953x; 1.6953x over previous
//
#include <hip/hip_runtime.h>
#include <hip/hip_bf16.h>
#include <math.h>

// ---------------------------------------------------------------------------
// GAT 2-layer forward. CSR aggregation (round-7 style), bf16 gather table,
// attention weights recomputed inline. Independent work heterogeneously
// fused into shared dispatches to hide latency + cut dispatch count:
//
//   1) gemm_hist<128>: blocks[0,ntiles) = gemm1 (+zero Z[0..3]);
//      blocks[ntiles,..) = dst-histogram (dst-partitioned %8, XCD-affine)
//   2) scan_blocks, 3) scan_finish  (rowptr prefix sums; cursor=rowptr copy)
//   4) scatter_z: blocks[0,2048) = dst-partitioned scatter -> esrc;
//      blocks[2048,..) = z1 edge-parallel sum into Z[0..1] (needs only gemm1)
//   5) csr_aggregate -> x2 (relu fused)
//   6) gemm_hist<64> with grid=ntiles (pure gemm2)
//   7) z_edge -> Z[2..3]
//   8) csr_aggregate -> out
//
// Global softmax denominator: max-shift skipped (logits bounded, exp safe —
// mathematically identical normalization).
// ---------------------------------------------------------------------------

__device__ __forceinline__ unsigned f2bf(float x) {  // fp32 -> bf16 (RNE)
  unsigned u = __float_as_uint(x);
  return (u + 0x7fffu + ((u >> 16) & 1u)) >> 16;
}
__device__ __forceinline__ float bflo(unsigned p) { return __uint_as_float(p << 16); }
__device__ __forceinline__ float bfhi(unsigned p) { return __uint_as_float(p & 0xffff0000u); }

// Register-tiled GEMM + fused scores; blocks >= ntiles run dst-histogram.
template <int FIN>
__global__ __launch_bounds__(256) void gemm_hist(
    const float* __restrict__ x, const float* __restrict__ W,
    const float* __restrict__ att, unsigned* __restrict__ hq,
    float* __restrict__ si, float* __restrict__ sj,
    float* __restrict__ Z, int N, int zero_z,
    const int* __restrict__ dstE, int* __restrict__ deg,
    int E, int Etot, int ntiles, int step) {
  const int tid = threadIdx.x;

  if ((int)blockIdx.x >= ntiles) {
    // ---- histogram part (dst-partitioned, XCD-affine via bid%8) ----
    int bid = blockIdx.x - ntiles;
    int p = bid & 7, sub = bid >> 3;
    int nsub = (gridDim.x - ntiles) >> 3;
    int lo = p * step, hi = lo + step;
    int stride = nsub * 256;
    for (int e = sub * 256 + tid; e < Etot; e += stride) {
      int d = (e < E) ? dstE[e] : e - E;
      if (d >= lo && d < hi) atomicAdd(&deg[d], 1);
    }
    return;
  }

  __shared__ __align__(16) float xs[32][68];
  __shared__ __align__(16) float ws[32][132];

  const int tc = tid & 31;
  const int tr = tid >> 5;
  const int lane = tid & 63;
  const int n0 = blockIdx.x * 64;

  if (zero_z && blockIdx.x == 0 && tid < 4) Z[tid] = 0.f;  // consumers are later dispatches

  const float4* x4 = (const float4*)x;
  const float4* W4 = (const float4*)W;

  float acc[8][4];
#pragma unroll
  for (int i = 0; i < 8; ++i)
#pragma unroll
    for (int j = 0; j < 4; ++j) acc[i][j] = 0.f;

  for (int kc = 0; kc < FIN; kc += 32) {
    const int kc4 = kc >> 2;
    __syncthreads();
#pragma unroll
    for (int r = 0; r < 2; ++r) {
      int i = tid + r * 256;
      int node = i >> 3, kq = i & 7;
      int gn = n0 + node;
      float4 v = make_float4(0.f, 0.f, 0.f, 0.f);
      if (gn < N) v = x4[(size_t)gn * (FIN / 4) + kc4 + kq];
      xs[kq * 4 + 0][node] = v.x;
      xs[kq * 4 + 1][node] = v.y;
      xs[kq * 4 + 2][node] = v.z;
      xs[kq * 4 + 3][node] = v.w;
    }
#pragma unroll
    for (int r = 0; r < 4; ++r) {
      int i = tid + r * 256;
      int col = i >> 3, kq = i & 7;
      float4 v = W4[(size_t)col * (FIN / 4) + kc4 + kq];
      ws[kq * 4 + 0][col] = v.x;
      ws[kq * 4 + 1][col] = v.y;
      ws[kq * 4 + 2][col] = v.z;
      ws[kq * 4 + 3][col] = v.w;
    }
    __syncthreads();
#pragma unroll
    for (int k = 0; k < 32; ++k) {
      float4 wv = *(const float4*)&ws[k][tc * 4];
      float4 a0 = *(const float4*)&xs[k][tr * 8];
      float4 a1 = *(const float4*)&xs[k][tr * 8 + 4];
      float av[8] = {a0.x, a0.y, a0.z, a0.w, a1.x, a1.y, a1.z, a1.w};
      float wvv[4] = {wv.x, wv.y, wv.z, wv.w};
#pragma unroll
      for (int i = 0; i < 8; ++i)
#pragma unroll
        for (int j = 0; j < 4; ++j) acc[i][j] += av[i] * wvv[j];
    }
  }

  // ------- epilogue: pack bf16x2 h + fused attention scores -------
  const int hd = tc >> 4;
  const int ch = (tc & 15) * 4;
  float ai[4], aj[4];
#pragma unroll
  for (int j = 0; j < 4; ++j) {
    ai[j] = att[hd * 128 + ch + j];
    aj[j] = att[hd * 128 + 64 + ch + j];
  }
#pragma unroll
  for (int i = 0; i < 8; ++i) {
    int node = n0 + tr * 8 + i;
    float sip = 0.f, sjp = 0.f;
    unsigned w[4];
#pragma unroll
    for (int j = 0; j < 4; ++j) {
      float v = acc[i][j];
      sip += v * ai[j];
      sjp += v * aj[j];
      float other = __shfl_xor(v, 16, 64);  // partner head, same channel
      float h0 = (tc < 16) ? v : other;
      float h1 = (tc < 16) ? other : v;
      w[j] = f2bf(h0) | (f2bf(h1) << 16);
    }
#pragma unroll
    for (int off = 8; off; off >>= 1) {
      sip += __shfl_down(sip, off, 64);
      sjp += __shfl_down(sjp, off, 64);
    }
    bool valid = node < N;
    if (valid && tc < 16) {
      *(uint4*)&hq[(size_t)node * 64 + ch] = make_uint4(w[0], w[1], w[2], w[3]);
    }
    if (valid && (lane & 15) == 0) {
      int hh = (lane >> 4) & 1;
      si[node * 2 + hh] = sip;
      sj[node * 2 + hh] = sjp;
    }
  }
}

// edge-parallel Z sum over the ORIGINAL edge list (order-independent)
__device__ __forceinline__ void z_edge_body(
    const int* __restrict__ srcE, const int* __restrict__ dstE,
    const float2* __restrict__ si2, const float2* __restrict__ sj2,
    float* __restrict__ Zp, int E, int Etot, int tid0, int stride) {
  float z0 = 0.f, z1 = 0.f;
  for (int e = tid0; e < Etot; e += stride) {
    int s, d;
    if (e < E) { s = srcE[e]; d = dstE[e]; } else { s = d = e - E; }
    float2 siv = si2[d];
    float2 sjv = sj2[s];
    float a0 = siv.x + sjv.x;
    float a1 = siv.y + sjv.y;
    a0 = a0 >= 0.f ? a0 : 0.2f * a0;
    a1 = a1 >= 0.f ? a1 : 0.2f * a1;
    z0 += __expf(a0); z1 += __expf(a1);
  }
  __shared__ float r0[4], r1[4];
  int lane = threadIdx.x & 63, w = threadIdx.x >> 6;
#pragma unroll
  for (int off = 32; off; off >>= 1) {
    z0 += __shfl_down(z0, off, 64);
    z1 += __shfl_down(z1, off, 64);
  }
  if (lane == 0) { r0[w] = z0; r1[w] = z1; }
  __syncthreads();
  if (threadIdx.x == 0) {
    atomicAdd(&Zp[0], r0[0] + r0[1] + r0[2] + r0[3]);
    atomicAdd(&Zp[1], r1[0] + r1[1] + r1[2] + r1[3]);
  }
}

__global__ __launch_bounds__(256) void z_edge(
    const int* __restrict__ srcE, const int* __restrict__ dstE,
    const float2* __restrict__ si2, const float2* __restrict__ sj2,
    float* __restrict__ Zp, int E, int Etot) {
  z_edge_body(srcE, dstE, si2, sj2, Zp, E, Etot,
              blockIdx.x * 256 + threadIdx.x, gridDim.x * 256);
}

__global__ __launch_bounds__(256) void scan_blocks(
    const int* __restrict__ deg, int* __restrict__ rowptr,
    int* __restrict__ bsum, int N) {
  __shared__ int ts[256];
  int b = blockIdx.x, t = threadIdx.x;
  int base = b * 1024 + t * 4;
  int v[4];
#pragma unroll
  for (int j = 0; j < 4; ++j) v[j] = (base + j < N) ? deg[base + j] : 0;
  int tot = v[0] + v[1] + v[2] + v[3];
  ts[t] = tot;
  __syncthreads();
#pragma unroll
  for (int off = 1; off < 256; off <<= 1) {
    int x = (t >= off) ? ts[t - off] : 0;
    __syncthreads();
    ts[t] += x;
    __syncthreads();
  }
  int run = ts[t] - tot;
#pragma unroll
  for (int j = 0; j < 4; ++j) {
    if (base + j < N) rowptr[base + j] = run;
    run += v[j];
  }
  if (t == 255) bsum[b] = ts[255];
}

// folds the bsum scan in: each block serially prefixes bsum (nb<=256) in LDS
__global__ __launch_bounds__(256) void scan_finish(
    int* __restrict__ rowptr, const int* __restrict__ bsum,
    int* __restrict__ cursor, int N, int Etot, int nb) {
  __shared__ int pre[256];
  if (threadIdx.x == 0) {
    int run = 0;
    for (int i = 0; i < nb; ++i) { pre[i] = run; run += bsum[i]; }
  }
  __syncthreads();
  int tid = blockIdx.x * blockDim.x + threadIdx.x;
  int stride = gridDim.x * blockDim.x;
  for (int i = tid; i < N; i += stride) {
    int v = rowptr[i] + pre[i >> 10];
    rowptr[i] = v;
    cursor[i] = v;
  }
  if (tid == 0) rowptr[N] = Etot;
}

// blocks[0,nscat): dst-partitioned scatter (XCD-affine %8);
// blocks[nscat,..): z1 edge-parallel sum (independent of the scatter)
__global__ __launch_bounds__(256) void scatter_z(
    const int* __restrict__ srcE, const int* __restrict__ dstE,
    int* __restrict__ cursor, int* __restrict__ esrc,
    const float2* __restrict__ si2, const float2* __restrict__ sj2,
    float* __restrict__ Zp, int E, int Etot, int step, int nscat) {
  if ((int)blockIdx.x >= nscat) {
    int tid0 = (blockIdx.x - nscat) * 256 + threadIdx.x;
    int stride = (gridDim.x - nscat) * 256;
    z_edge_body(srcE, dstE, si2, sj2, Zp, E, Etot, tid0, stride);
    return;
  }
  const int p = blockIdx.x & 7;
  const int sub = blockIdx.x >> 3;
  const int nsub = nscat >> 3;
  const int lo = p * step;
  const int hi = lo + step;
  int stride = nsub * 256;
  for (int e = sub * 256 + threadIdx.x; e < Etot; e += stride) {
    int d = (e < E) ? dstE[e] : e - E;
    if (d >= lo && d < hi) {
      int s = (e < E) ? srcE[e] : d;
      int pos = atomicAdd(&cursor[d], 1);
      esrc[pos] = s;
    }
  }
}

// one wave per dst node (scalarized): weight recomputed inline,
// acc += w * hq[src], fused head-mean + bias (+relu) epilogue
__global__ __launch_bounds__(256) void csr_aggregate(
    const int* __restrict__ rowptr, const int* __restrict__ esrc,
    const unsigned* __restrict__ hq, const float2* __restrict__ si2,
    const float2* __restrict__ sj2, const float* __restrict__ Zp,
    const float* __restrict__ bias, float* __restrict__ out,
    int N, int do_relu) {
  int lane = threadIdx.x & 63;
  int wid = (blockIdx.x * blockDim.x + threadIdx.x) >> 6;
  int nw = (gridDim.x * blockDim.x) >> 6;
  float z0 = 1.f / (Zp[0] + 1e-10f);
  float z1 = 1.f / (Zp[1] + 1e-10f);
  float bv = bias[lane];
  for (int n0 = wid; n0 < N; n0 += nw) {
    // n is wave-uniform; force SGPR so the rowptr/esrc/sj2 chain is scalar
    int n = __builtin_amdgcn_readfirstlane(n0);
    int beg = rowptr[n], end = rowptr[n + 1];
    float2 siv = si2[n];
    float acc0 = 0.f, acc1 = 0.f;
    int k = beg;
    for (; k + 4 <= end; k += 4) {
      int s0 = esrc[k], s1 = esrc[k + 1], s2 = esrc[k + 2], s3 = esrc[k + 3];
      float2 j0 = sj2[s0], j1 = sj2[s1], j2 = sj2[s2], j3 = sj2[s3];
      unsigned p0 = hq[(size_t)s0 * 64 + lane];
      unsigned p1 = hq[(size_t)s1 * 64 + lane];
      unsigned p2 = hq[(size_t)s2 * 64 + lane];
      unsigned p3 = hq[(size_t)s3 * 64 + lane];
      float a00 = siv.x + j0.x, a01 = siv.y + j0.y;
      float a10 = siv.x + j1.x, a11 = siv.y + j1.y;
      float a20 = siv.x + j2.x, a21 = siv.y + j2.y;
      float a30 = siv.x + j3.x, a31 = siv.y + j3.y;
      a00 = a00 >= 0.f ? a00 : 0.2f * a00;  a01 = a01 >= 0.f ? a01 : 0.2f * a01;
      a10 = a10 >= 0.f ? a10 : 0.2f * a10;  a11 = a11 >= 0.f ? a11 : 0.2f * a11;
      a20 = a20 >= 0.f ? a20 : 0.2f * a20;  a21 = a21 >= 0.f ? a21 : 0.2f * a21;
      a30 = a30 >= 0.f ? a30 : 0.2f * a30;  a31 = a31 >= 0.f ? a31 : 0.2f * a31;
      float w00 = __expf(a00), w01 = __expf(a01);
      float w10 = __expf(a10), w11 = __expf(a11);
      float w20 = __expf(a20), w21 = __expf(a21);
      float w30 = __expf(a30), w31 = __expf(a31);
      acc0 += bflo(p0) * w00 + bflo(p1) * w10 + bflo(p2) * w20 + bflo(p3) * w30;
      acc1 += bfhi(p0) * w01 + bfhi(p1) * w11 + bfhi(p2) * w21 + bfhi(p3) * w31;
    }
    for (; k < end; ++k) {
      int s = esrc[k];
      float2 jv = sj2[s];
      unsigned p = hq[(size_t)s * 64 + lane];
      float a0 = siv.x + jv.x, a1 = siv.y + jv.y;
      a0 = a0 >= 0.f ? a0 : 0.2f * a0;
      a1 = a1 >= 0.f ? a1 : 0.2f * a1;
      acc0 += bflo(p) * __expf(a0);
      acc1 += bfhi(p) * __expf(a1);
    }
    float r = 0.5f * (acc0 * z0 + acc1 * z1) + bv;
    if (do_relu) r = fmaxf(r, 0.f);
    out[(size_t)n * 64 + lane] = r;
  }
}

extern "C" void kernel_launch(void* const* d_in, const int* in_sizes, int n_in,
                              void* d_out, int out_size, void* d_ws, size_t ws_size,
                              hipStream_t stream) {
  const float* x    = (const float*)d_in[0];
  const int*   ei   = (const int*)d_in[1];   // [2, E] int32
  const float* W1   = (const float*)d_in[2];
  const float* att1 = (const float*)d_in[3];
  const float* b1   = (const float*)d_in[4];
  const float* W2   = (const float*)d_in[5];
  const float* att2 = (const float*)d_in[6];
  const float* b2   = (const float*)d_in[7];
  float* out = (float*)d_out;

  const int N = in_sizes[0] / 128;   // 50000
  const int E = in_sizes[1] / 2;     // 800000
  const int Etot = E + N;
  const int* srcE = ei;
  const int* dstE = ei + E;

  // workspace layout (all segments 16B-aligned)
  unsigned* hq = (unsigned*)d_ws;                 // N*64 packed bf16x2
  float* si    = (float*)(hq + (size_t)N * 64);   // N*2
  float* sj    = si + (size_t)N * 2;              // N*2
  float* Z     = sj + (size_t)N * 2;              // 4 (L1: Z[0..1], L2: Z[2..3])
  float* x2    = Z + 4;                           // N*64
  int* rowptr  = (int*)(x2 + (size_t)N * 64);     // N+1
  int* cursor  = rowptr + (N + 1);                // N (deg histogram too)
  int* esrc    = cursor + N;                      // Etot
  int* bsum    = esrc + Etot;                     // up to 256

  dim3 blk(256);
  int nb = (N + 1023) / 1024;
  int ntiles = (N + 63) / 64;
  int step = (N + 7) / 8;

  hipMemsetAsync(cursor, 0, (size_t)N * sizeof(int), stream);

  // 1) gemm1 + dst-histogram fused (independent work, one dispatch)
  gemm_hist<128><<<ntiles + 2048, blk, 0, stream>>>(
      x, W1, att1, hq, si, sj, Z, N, /*zero_z=*/1,
      dstE, cursor, E, Etot, ntiles, step);
  // 2,3) rowptr prefix
  scan_blocks<<<nb, blk, 0, stream>>>(cursor, rowptr, bsum, N);
  scan_finish<<<256, blk, 0, stream>>>(rowptr, bsum, cursor, N, Etot, nb);
  // 4) scatter + z1 fused (z1 needs only gemm1; scatter needs only scan)
  scatter_z<<<2048 + 256, blk, 0, stream>>>(
      srcE, dstE, cursor, esrc, (const float2*)si, (const float2*)sj,
      Z, E, Etot, step, /*nscat=*/2048);
  // 5) layer-1 aggregation -> x2 (relu fused)
  csr_aggregate<<<4096, blk, 0, stream>>>(rowptr, esrc, hq, (const float2*)si,
                                          (const float2*)sj, Z, b1, x2, N, 1);
  // 6) gemm2 (grid=ntiles: hist branch never taken)
  gemm_hist<64><<<ntiles, blk, 0, stream>>>(
      x2, W2, att2, hq, si, sj, Z, N, /*zero_z=*/0,
      dstE, cursor, E, Etot, ntiles, step);
  // 7) z2
  z_edge<<<256, blk, 0, stream>>>(srcE, dstE, (const float2*)si,
                                  (const float2*)sj, Z + 2, E, Etot);
  // 8) layer-2 aggregation -> out
  csr_aggregate<<<4096, blk, 0, stream>>>(rowptr, esrc, hq, (const float2*)si,
                                          (const float2*)sj, Z + 2, b2, out, N, 0);
}

// Round 10
// 294.377 us; speedup vs baseline: 1.8325x; 1.0809x over previous
//
#include <hip/hip_runtime.h>
#include <hip/hip_bf16.h>
#include <math.h>

// ---------------------------------------------------------------------------
// GAT 2-layer forward. CSR aggregation, bf16 gather table, inline attention
// weights. Heterogeneous fusion with co-residency-aware grids:
//
//   1) gemm_hist<128>: blocks[0,ntiles)=gemm1(+zero Z); blocks[ntiles,+1264)
//      = dst-histogram over real edges (dst-partitioned %8). 782+1264 <= 2048
//      -> fully co-resident, hist hides under gemm.
//   2) scan_blocks, 3) scan_finish (rowptr prefix; cursor copy)
//   4) scatter_z: blocks[0,256)=z1 edge-parallel (FIRST so it co-schedules);
//      blocks[256,256+1792)=dst-partitioned scatter. 2048 total = capacity.
//   5) csr_aggregate -> x2 (self-loop term inline; relu fused)
//   6) gemm_hist<64> grid=ntiles (pure gemm2)
//   7) z_edge -> Z[2..3]
//   8) csr_aggregate -> out
//
// CSR holds only the E real edges; self-loops are applied inline in the
// aggregator. Z sums include self-loops (z walks the original list + loops).
// Global softmax max-shift skipped (logits bounded — identical result).
// ---------------------------------------------------------------------------

#define NHIST 1264   // 8*158
#define NZ    256
#define NSCAT 1792   // 8*224; NZ+NSCAT = 2048 = full co-residency

__device__ __forceinline__ unsigned f2bf(float x) {  // fp32 -> bf16 (RNE)
  unsigned u = __float_as_uint(x);
  return (u + 0x7fffu + ((u >> 16) & 1u)) >> 16;
}
__device__ __forceinline__ float bflo(unsigned p) { return __uint_as_float(p << 16); }
__device__ __forceinline__ float bfhi(unsigned p) { return __uint_as_float(p & 0xffff0000u); }

// Register-tiled GEMM + fused scores; blocks >= ntiles run dst-histogram.
template <int FIN>
__global__ __launch_bounds__(256) void gemm_hist(
    const float* __restrict__ x, const float* __restrict__ W,
    const float* __restrict__ att, unsigned* __restrict__ hq,
    float* __restrict__ si, float* __restrict__ sj,
    float* __restrict__ Z, int N, int zero_z,
    const int* __restrict__ dstE, int* __restrict__ deg,
    int E, int ntiles, int step) {
  const int tid = threadIdx.x;

  if ((int)blockIdx.x >= ntiles) {
    // ---- histogram over real edges (dst-partitioned, %8 XCD-affine) ----
    int bid = blockIdx.x - ntiles;
    int p = bid & 7, sub = bid >> 3;
    int nsub = NHIST >> 3;
    int lo = p * step, hi = lo + step;
    int stride = nsub * 256;
    for (int e = sub * 256 + tid; e < E; e += stride) {
      int d = dstE[e];
      if (d >= lo && d < hi) atomicAdd(&deg[d], 1);
    }
    return;
  }

  __shared__ __align__(16) float xs[32][68];
  __shared__ __align__(16) float ws[32][132];

  const int tc = tid & 31;
  const int tr = tid >> 5;
  const int lane = tid & 63;
  const int n0 = blockIdx.x * 64;

  if (zero_z && blockIdx.x == 0 && tid < 4) Z[tid] = 0.f;  // consumers are later dispatches

  const float4* x4 = (const float4*)x;
  const float4* W4 = (const float4*)W;

  float acc[8][4];
#pragma unroll
  for (int i = 0; i < 8; ++i)
#pragma unroll
    for (int j = 0; j < 4; ++j) acc[i][j] = 0.f;

  for (int kc = 0; kc < FIN; kc += 32) {
    const int kc4 = kc >> 2;
    __syncthreads();
#pragma unroll
    for (int r = 0; r < 2; ++r) {
      int i = tid + r * 256;
      int node = i >> 3, kq = i & 7;
      int gn = n0 + node;
      float4 v = make_float4(0.f, 0.f, 0.f, 0.f);
      if (gn < N) v = x4[(size_t)gn * (FIN / 4) + kc4 + kq];
      xs[kq * 4 + 0][node] = v.x;
      xs[kq * 4 + 1][node] = v.y;
      xs[kq * 4 + 2][node] = v.z;
      xs[kq * 4 + 3][node] = v.w;
    }
#pragma unroll
    for (int r = 0; r < 4; ++r) {
      int i = tid + r * 256;
      int col = i >> 3, kq = i & 7;
      float4 v = W4[(size_t)col * (FIN / 4) + kc4 + kq];
      ws[kq * 4 + 0][col] = v.x;
      ws[kq * 4 + 1][col] = v.y;
      ws[kq * 4 + 2][col] = v.z;
      ws[kq * 4 + 3][col] = v.w;
    }
    __syncthreads();
#pragma unroll
    for (int k = 0; k < 32; ++k) {
      float4 wv = *(const float4*)&ws[k][tc * 4];
      float4 a0 = *(const float4*)&xs[k][tr * 8];
      float4 a1 = *(const float4*)&xs[k][tr * 8 + 4];
      float av[8] = {a0.x, a0.y, a0.z, a0.w, a1.x, a1.y, a1.z, a1.w};
      float wvv[4] = {wv.x, wv.y, wv.z, wv.w};
#pragma unroll
      for (int i = 0; i < 8; ++i)
#pragma unroll
        for (int j = 0; j < 4; ++j) acc[i][j] += av[i] * wvv[j];
    }
  }

  // ------- epilogue: pack bf16x2 h + fused attention scores -------
  const int hd = tc >> 4;
  const int ch = (tc & 15) * 4;
  float ai[4], aj[4];
#pragma unroll
  for (int j = 0; j < 4; ++j) {
    ai[j] = att[hd * 128 + ch + j];
    aj[j] = att[hd * 128 + 64 + ch + j];
  }
#pragma unroll
  for (int i = 0; i < 8; ++i) {
    int node = n0 + tr * 8 + i;
    float sip = 0.f, sjp = 0.f;
    unsigned w[4];
#pragma unroll
    for (int j = 0; j < 4; ++j) {
      float v = acc[i][j];
      sip += v * ai[j];
      sjp += v * aj[j];
      float other = __shfl_xor(v, 16, 64);  // partner head, same channel
      float h0 = (tc < 16) ? v : other;
      float h1 = (tc < 16) ? other : v;
      w[j] = f2bf(h0) | (f2bf(h1) << 16);
    }
#pragma unroll
    for (int off = 8; off; off >>= 1) {
      sip += __shfl_down(sip, off, 64);
      sjp += __shfl_down(sjp, off, 64);
    }
    bool valid = node < N;
    if (valid && tc < 16) {
      *(uint4*)&hq[(size_t)node * 64 + ch] = make_uint4(w[0], w[1], w[2], w[3]);
    }
    if (valid && (lane & 15) == 0) {
      int hh = (lane >> 4) & 1;
      si[node * 2 + hh] = sip;
      sj[node * 2 + hh] = sjp;
    }
  }
}

// edge-parallel Z sum over the ORIGINAL edge list incl. self-loops
__device__ __forceinline__ void z_edge_body(
    const int* __restrict__ srcE, const int* __restrict__ dstE,
    const float2* __restrict__ si2, const float2* __restrict__ sj2,
    float* __restrict__ Zp, int E, int Etot, int tid0, int stride) {
  float z0 = 0.f, z1 = 0.f;
  for (int e = tid0; e < Etot; e += stride) {
    int s, d;
    if (e < E) { s = srcE[e]; d = dstE[e]; } else { s = d = e - E; }
    float2 siv = si2[d];
    float2 sjv = sj2[s];
    float a0 = siv.x + sjv.x;
    float a1 = siv.y + sjv.y;
    a0 = a0 >= 0.f ? a0 : 0.2f * a0;
    a1 = a1 >= 0.f ? a1 : 0.2f * a1;
    z0 += __expf(a0); z1 += __expf(a1);
  }
  __shared__ float r0[4], r1[4];
  int lane = threadIdx.x & 63, w = threadIdx.x >> 6;
#pragma unroll
  for (int off = 32; off; off >>= 1) {
    z0 += __shfl_down(z0, off, 64);
    z1 += __shfl_down(z1, off, 64);
  }
  if (lane == 0) { r0[w] = z0; r1[w] = z1; }
  __syncthreads();
  if (threadIdx.x == 0) {
    atomicAdd(&Zp[0], r0[0] + r0[1] + r0[2] + r0[3]);
    atomicAdd(&Zp[1], r1[0] + r1[1] + r1[2] + r1[3]);
  }
}

__global__ __launch_bounds__(256) void z_edge(
    const int* __restrict__ srcE, const int* __restrict__ dstE,
    const float2* __restrict__ si2, const float2* __restrict__ sj2,
    float* __restrict__ Zp, int E, int Etot) {
  z_edge_body(srcE, dstE, si2, sj2, Zp, E, Etot,
              blockIdx.x * 256 + threadIdx.x, gridDim.x * 256);
}

__global__ __launch_bounds__(256) void scan_blocks(
    const int* __restrict__ deg, int* __restrict__ rowptr,
    int* __restrict__ bsum, int N) {
  __shared__ int ts[256];
  int b = blockIdx.x, t = threadIdx.x;
  int base = b * 1024 + t * 4;
  int v[4];
#pragma unroll
  for (int j = 0; j < 4; ++j) v[j] = (base + j < N) ? deg[base + j] : 0;
  int tot = v[0] + v[1] + v[2] + v[3];
  ts[t] = tot;
  __syncthreads();
#pragma unroll
  for (int off = 1; off < 256; off <<= 1) {
    int x = (t >= off) ? ts[t - off] : 0;
    __syncthreads();
    ts[t] += x;
    __syncthreads();
  }
  int run = ts[t] - tot;
#pragma unroll
  for (int j = 0; j < 4; ++j) {
    if (base + j < N) rowptr[base + j] = run;
    run += v[j];
  }
  if (t == 255) bsum[b] = ts[255];
}

// folds the bsum scan in: serial prefix of bsum (nb<=256) in LDS per block
__global__ __launch_bounds__(256) void scan_finish(
    int* __restrict__ rowptr, const int* __restrict__ bsum,
    int* __restrict__ cursor, int N, int Eall, int nb) {
  __shared__ int pre[256];
  if (threadIdx.x == 0) {
    int run = 0;
    for (int i = 0; i < nb; ++i) { pre[i] = run; run += bsum[i]; }
  }
  __syncthreads();
  int tid = blockIdx.x * blockDim.x + threadIdx.x;
  int stride = gridDim.x * blockDim.x;
  for (int i = tid; i < N; i += stride) {
    int v = rowptr[i] + pre[i >> 10];
    rowptr[i] = v;
    cursor[i] = v;
  }
  if (tid == 0) rowptr[N] = Eall;
}

// blocks[0,NZ): z1 edge-parallel (dispatched FIRST -> co-schedules under
// the scatter); blocks[NZ,NZ+NSCAT): dst-partitioned scatter (%8 affine).
__global__ __launch_bounds__(256) void scatter_z(
    const int* __restrict__ srcE, const int* __restrict__ dstE,
    int* __restrict__ cursor, int* __restrict__ esrc,
    const float2* __restrict__ si2, const float2* __restrict__ sj2,
    float* __restrict__ Zp, int E, int Etot, int step) {
  if ((int)blockIdx.x < NZ) {
    z_edge_body(srcE, dstE, si2, sj2, Zp, E, Etot,
                blockIdx.x * 256 + threadIdx.x, NZ * 256);
    return;
  }
  const int bid = blockIdx.x - NZ;
  const int p = bid & 7;
  const int sub = bid >> 3;
  const int nsub = NSCAT >> 3;
  const int lo = p * step;
  const int hi = lo + step;
  int stride = nsub * 256;
  for (int e = sub * 256 + threadIdx.x; e < E; e += stride) {
    int d = dstE[e];
    if (d >= lo && d < hi) {
      int s = srcE[e];
      int pos = atomicAdd(&cursor[d], 1);
      esrc[pos] = s;
    }
  }
}

// one wave per dst node (scalarized): inline attention weights, inline
// self-loop term, acc += w * hq[src], fused head-mean + bias (+relu)
__global__ __launch_bounds__(256) void csr_aggregate(
    const int* __restrict__ rowptr, const int* __restrict__ esrc,
    const unsigned* __restrict__ hq, const float2* __restrict__ si2,
    const float2* __restrict__ sj2, const float* __restrict__ Zp,
    const float* __restrict__ bias, float* __restrict__ out,
    int N, int do_relu) {
  int lane = threadIdx.x & 63;
  int wid = (blockIdx.x * blockDim.x + threadIdx.x) >> 6;
  int nw = (gridDim.x * blockDim.x) >> 6;
  float z0 = 1.f / (Zp[0] + 1e-10f);
  float z1 = 1.f / (Zp[1] + 1e-10f);
  float bv = bias[lane];
  for (int n0 = wid; n0 < N; n0 += nw) {
    // n is wave-uniform; force SGPR so the rowptr/esrc/sj2 chain is scalar
    int n = __builtin_amdgcn_readfirstlane(n0);
    int beg = rowptr[n], end = rowptr[n + 1];
    float2 siv = si2[n];
    // self-loop term (src = dst = n)
    float acc0, acc1;
    {
      float2 jv = sj2[n];
      unsigned p = hq[(size_t)n * 64 + lane];
      float a0 = siv.x + jv.x, a1 = siv.y + jv.y;
      a0 = a0 >= 0.f ? a0 : 0.2f * a0;
      a1 = a1 >= 0.f ? a1 : 0.2f * a1;
      acc0 = bflo(p) * __expf(a0);
      acc1 = bfhi(p) * __expf(a1);
    }
    int k = beg;
    for (; k + 4 <= end; k += 4) {
      int s0 = esrc[k], s1 = esrc[k + 1], s2 = esrc[k + 2], s3 = esrc[k + 3];
      float2 j0 = sj2[s0], j1 = sj2[s1], j2 = sj2[s2], j3 = sj2[s3];
      unsigned p0 = hq[(size_t)s0 * 64 + lane];
      unsigned p1 = hq[(size_t)s1 * 64 + lane];
      unsigned p2 = hq[(size_t)s2 * 64 + lane];
      unsigned p3 = hq[(size_t)s3 * 64 + lane];
      float a00 = siv.x + j0.x, a01 = siv.y + j0.y;
      float a10 = siv.x + j1.x, a11 = siv.y + j1.y;
      float a20 = siv.x + j2.x, a21 = siv.y + j2.y;
      float a30 = siv.x + j3.x, a31 = siv.y + j3.y;
      a00 = a00 >= 0.f ? a00 : 0.2f * a00;  a01 = a01 >= 0.f ? a01 : 0.2f * a01;
      a10 = a10 >= 0.f ? a10 : 0.2f * a10;  a11 = a11 >= 0.f ? a11 : 0.2f * a11;
      a20 = a20 >= 0.f ? a20 : 0.2f * a20;  a21 = a21 >= 0.f ? a21 : 0.2f * a21;
      a30 = a30 >= 0.f ? a30 : 0.2f * a30;  a31 = a31 >= 0.f ? a31 : 0.2f * a31;
      float w00 = __expf(a00), w01 = __expf(a01);
      float w10 = __expf(a10), w11 = __expf(a11);
      float w20 = __expf(a20), w21 = __expf(a21);
      float w30 = __expf(a30), w31 = __expf(a31);
      acc0 += bflo(p0) * w00 + bflo(p1) * w10 + bflo(p2) * w20 + bflo(p3) * w30;
      acc1 += bfhi(p0) * w01 + bfhi(p1) * w11 + bfhi(p2) * w21 + bfhi(p3) * w31;
    }
    for (; k < end; ++k) {
      int s = esrc[k];
      float2 jv = sj2[s];
      unsigned p = hq[(size_t)s * 64 + lane];
      float a0 = siv.x + jv.x, a1 = siv.y + jv.y;
      a0 = a0 >= 0.f ? a0 : 0.2f * a0;
      a1 = a1 >= 0.f ? a1 : 0.2f * a1;
      acc0 += bflo(p) * __expf(a0);
      acc1 += bfhi(p) * __expf(a1);
    }
    float r = 0.5f * (acc0 * z0 + acc1 * z1) + bv;
    if (do_relu) r = fmaxf(r, 0.f);
    out[(size_t)n * 64 + lane] = r;
  }
}

extern "C" void kernel_launch(void* const* d_in, const int* in_sizes, int n_in,
                              void* d_out, int out_size, void* d_ws, size_t ws_size,
                              hipStream_t stream) {
  const float* x    = (const float*)d_in[0];
  const int*   ei   = (const int*)d_in[1];   // [2, E] int32
  const float* W1   = (const float*)d_in[2];
  const float* att1 = (const float*)d_in[3];
  const float* b1   = (const float*)d_in[4];
  const float* W2   = (const float*)d_in[5];
  const float* att2 = (const float*)d_in[6];
  const float* b2   = (const float*)d_in[7];
  float* out = (float*)d_out;

  const int N = in_sizes[0] / 128;   // 50000
  const int E = in_sizes[1] / 2;     // 800000
  const int Etot = E + N;            // incl. self-loops (Z sums only)
  const int* srcE = ei;
  const int* dstE = ei + E;

  // workspace layout (all segments 16B-aligned)
  unsigned* hq = (unsigned*)d_ws;                 // N*64 packed bf16x2
  float* si    = (float*)(hq + (size_t)N * 64);   // N*2
  float* sj    = si + (size_t)N * 2;              // N*2
  float* Z     = sj + (size_t)N * 2;              // 4 (L1: Z[0..1], L2: Z[2..3])
  float* x2    = Z + 4;                           // N*64
  int* rowptr  = (int*)(x2 + (size_t)N * 64);     // N+1
  int* cursor  = rowptr + (N + 1);                // N (deg histogram too)
  int* esrc    = cursor + N;                      // E (real edges only)
  int* bsum    = esrc + E;                        // up to 256

  dim3 blk(256);
  int nb = (N + 1023) / 1024;
  int ntiles = (N + 63) / 64;
  int step = (N + 7) / 8;

  hipMemsetAsync(cursor, 0, (size_t)N * sizeof(int), stream);

  // 1) gemm1 + dst-histogram fused (782+1264 = co-resident)
  gemm_hist<128><<<ntiles + NHIST, blk, 0, stream>>>(
      x, W1, att1, hq, si, sj, Z, N, /*zero_z=*/1,
      dstE, cursor, E, ntiles, step);
  // 2,3) rowptr prefix
  scan_blocks<<<nb, blk, 0, stream>>>(cursor, rowptr, bsum, N);
  scan_finish<<<256, blk, 0, stream>>>(rowptr, bsum, cursor, N, E, nb);
  // 4) z1 (first 256 blocks, co-scheduled) + scatter (1792 blocks)
  scatter_z<<<NZ + NSCAT, blk, 0, stream>>>(
      srcE, dstE, cursor, esrc, (const float2*)si, (const float2*)sj,
      Z, E, Etot, step);
  // 5) layer-1 aggregation -> x2 (self-loop inline; relu fused)
  csr_aggregate<<<4096, blk, 0, stream>>>(rowptr, esrc, hq, (const float2*)si,
                                          (const float2*)sj, Z, b1, x2, N, 1);
  // 6) gemm2 (grid=ntiles: hist branch never taken)
  gemm_hist<64><<<ntiles, blk, 0, stream>>>(
      x2, W2, att2, hq, si, sj, Z, N, /*zero_z=*/0,
      dstE, cursor, E, ntiles, step);
  // 7) z2
  z_edge<<<NZ, blk, 0, stream>>>(srcE, dstE, (const float2*)si,
                                 (const float2*)sj, Z + 2, E, Etot);
  // 8) layer-2 aggregation -> out
  csr_aggregate<<<4096, blk, 0, stream>>>(rowptr, esrc, hq, (const float2*)si,
                                          (const float2*)sj, Z + 2, b2, out, N, 0);
}